// Round 4
// baseline (122.455 us; speedup 1.0000x reference)
//
#include <hip/hip_runtime.h>

// Problem constants
#define HW 4096           // H*W
#define CHW 262144        // C*H*W
#define OUT_ELEMS 4194304 // B*C*H*W
#define FLT_BIG 3.4e38f

typedef __attribute__((ext_vector_type(8))) short  short8;   // MFMA A/B frag (4 VGPR)
typedef __attribute__((ext_vector_type(4))) float  floatx4;  // MFMA C/D frag
typedef __attribute__((ext_vector_type(4))) int    intx4;

// ws layout (no zero-init needed -- every byte read is written first):
//   [0,2048)        enorm f32[512]   -- holds -0.5*||e||^2 (prescaled)
//   [4096,135168)   planes_frag u16 (128 KB, fragment-major split-bf16 codebook)
//   [135168,167936) ws_sse double[4096]  (per-block SSE, plain stores)

__device__ __forceinline__ unsigned bf16_rne(float f) {
    unsigned u = __float_as_uint(f);
    return (u + 0x7FFFu + ((u >> 16) & 1u)) >> 16;  // RNE bf16 bits
}

__device__ __forceinline__ void split8(const float* f, intx4* hi, intx4* lo) {
    unsigned h[4], l[4];
#pragma unroll
    for (int j = 0; j < 4; ++j) {
        const unsigned h0 = bf16_rne(f[2 * j]);
        const unsigned h1 = bf16_rne(f[2 * j + 1]);
        const float hf0 = __uint_as_float(h0 << 16);
        const float hf1 = __uint_as_float(h1 << 16);
        const unsigned l0 = bf16_rne(f[2 * j] - hf0);
        const unsigned l1 = bf16_rne(f[2 * j + 1] - hf1);
        h[j] = h0 | (h1 << 16);
        l[j] = l0 | (l1 << 16);
    }
    *hi = intx4{(int)h[0], (int)h[1], (int)h[2], (int)h[3]};
    *lo = intx4{(int)l[0], (int)l[1], (int)l[2], (int)l[3]};
}

// prep: 128 blocks x 256 threads; 4 codes/block (1 wave per code), single
// iteration. enorm stored PRESCALED as -0.5*||e||^2.
__global__ void vq_prep(const float* __restrict__ emb,
                        unsigned short* __restrict__ pfrag,
                        float* __restrict__ enorm) {
    const int t = threadIdx.x;
    const int lane = t & 63;
    const int code = (blockIdx.x << 2) + (t >> 6);
    const int c = lane;
    const float v = emb[(code << 6) + c];            // 256B coalesced per wave
    const unsigned hb = bf16_rne(v);
    const float hf    = __uint_as_float(hb << 16);
    const unsigned lb = bf16_rne(v - hf);
    const int nc = code >> 6, grp = (code & 63) >> 4, n = code & 15;
    const int q = (c & 31) >> 3, o = c & 7;
    const int jh = c >> 5;        // eh element e=c
    const int jl = 2 + (c >> 5);  // el element e=64+c
    pfrag[((((size_t)(nc*4 + jh)*4 + grp)*4 + q)*16 + n)*8 + o] = (unsigned short)hb;
    pfrag[((((size_t)(nc*4 + jl)*4 + grp)*4 + q)*16 + n)*8 + o] = (unsigned short)lb;
    float s = v * v;
#pragma unroll
    for (int off = 32; off > 0; off >>= 1) s += __shfl_xor(s, off, 64);
    if (lane == 0) enorm[code] = -0.5f * s;
}

// Main: R15 = R14 core at half block size, double supply (R10->R11 lever,
// one level down). 4096 blocks x 128 threads; 16 rows(w)/block; 2 waves =
// the two code-halves of one 16-row M-tile. Total MFMA/VALU/verify work
// unchanged; per-block serial chain halves; 16 blocks/CU exactly.
// Also: finalize phase merged into epilogue (every thread redundantly
// computes its row's fp64 winner from parts[] -- LDS broadcast -- instead
// of a serial t<32 phase + extra sync + qidx round-trip). 4 syncs, was 5.
// parts padded [8][17] to kill 4-way f64 bank aliasing.
// Carried (R12-R14 verified): swapped MFMA operands (codes=A, x=B; acc IS
// the score), enorm off the MFMA critical path, 2-round butterfly,
// NO device-scope atomics anywhere (R13 post-mortem).
__global__ __launch_bounds__(128)
void vq_main(const float* __restrict__ x_in, const float* __restrict__ emb,
             const unsigned short* __restrict__ pfrag,
             const float* __restrict__ enorm,
             float* __restrict__ out, float* __restrict__ idx_out,
             double* __restrict__ ws_sse) {
    __shared__ float  b1s[2][16], b2s[2][16];
    __shared__ int    i1s[2][16], i2s[2][16];
    __shared__ int    c1i[16], c2i[16];
    __shared__ double parts[8][17];
    __shared__ double ls_red[2];

    const int t     = threadIdx.x;
    const int lane  = t & 63;
    const int wv    = t >> 6;           // 0/1
    const int col   = lane & 15;        // w-row within the 16-w tile
    const int quad  = lane >> 4;
    const int blk   = blockIdx.x;
    const int khalf = wv;               // code-half of each 64-chunk
    const int ncol0 = khalf << 5;
    const int wq  = blk & 3;            // which 16-w quarter of the stripe
    const int bh  = blk >> 2;
    const int b = bh >> 6, h = bh & 63;
    const float* xb = x_in + (size_t)b * CHW + h * 64 + (wq << 4);

    // ---- X-frags: one 16-row M-tile, direct from BCHW global (coalesced),
    // split-bf16, register-resident. Used as the MFMA *B* operand. ----
    short8 Xh[2], Xl[2];
#pragma unroll
    for (int u = 0; u < 2; ++u) {
        float f[8];
#pragma unroll
        for (int j = 0; j < 8; ++j) {
            const int c = (u << 5) + (quad << 3) + j;
            f[j] = xb[(size_t)c * HW + col];
        }
        intx4 hi, lo;
        split8(f, &hi, &lo);
        Xh[u] = __builtin_bit_cast(short8, hi);
        Xl[u] = __builtin_bit_cast(short8, lo);
    }

    // Two per-lane top-2 tracks (nt=0 / nt=1) for ILP; merged before butterfly.
    float B1a = -FLT_BIG, B2a = -FLT_BIG, B1b = -FLT_BIG, B2b = -FLT_BIG;
    int   I1a = 0x3FFFFFFF, I2a = 0x3FFFFFFF, I1b = 0x3FFFFFFF, I2b = 0x3FFFFFFF;

    const char*  pf  = (const char*)pfrag + (size_t)lane * 16 + ((size_t)khalf << 11);
    const float* enp = enorm + ncol0 + (quad << 2);

#pragma unroll 2
    for (int nc = 0; nc < 8; ++nc) {
        const char* base = pf + ((size_t)nc << 14);
        const int K0 = nc << 6;
        // -0.5*||e||^2 for this lane's 8 codes; loads issue here, first use is
        // at selection below -> fully hidden under the MFMA chain.
        const floatx4 e0v = *(const floatx4*)(enp + K0);
        const floatx4 e1v = *(const floatx4*)(enp + K0 + 16);
        floatx4 a0{0.f,0.f,0.f,0.f}, a1{0.f,0.f,0.f,0.f};
#define BLD(j, g) (*(const short8*)(base + ((j) << 12) + ((g) << 10)))
        {   // j=0: eh c[0,32) x {xh,xl}
            const short8 e0 = BLD(0, 0), e1 = BLD(0, 1);
            a0 = __builtin_amdgcn_mfma_f32_16x16x32_bf16(e0, Xh[0], a0, 0, 0, 0);
            a1 = __builtin_amdgcn_mfma_f32_16x16x32_bf16(e1, Xh[0], a1, 0, 0, 0);
            a0 = __builtin_amdgcn_mfma_f32_16x16x32_bf16(e0, Xl[0], a0, 0, 0, 0);
            a1 = __builtin_amdgcn_mfma_f32_16x16x32_bf16(e1, Xl[0], a1, 0, 0, 0);
        }
        {   // j=1: eh c[32,64) x {xh,xl}
            const short8 e0 = BLD(1, 0), e1 = BLD(1, 1);
            a0 = __builtin_amdgcn_mfma_f32_16x16x32_bf16(e0, Xh[1], a0, 0, 0, 0);
            a1 = __builtin_amdgcn_mfma_f32_16x16x32_bf16(e1, Xh[1], a1, 0, 0, 0);
            a0 = __builtin_amdgcn_mfma_f32_16x16x32_bf16(e0, Xl[1], a0, 0, 0, 0);
            a1 = __builtin_amdgcn_mfma_f32_16x16x32_bf16(e1, Xl[1], a1, 0, 0, 0);
        }
        {   // j=2: el c[0,32) x xh
            const short8 e0 = BLD(2, 0), e1 = BLD(2, 1);
            a0 = __builtin_amdgcn_mfma_f32_16x16x32_bf16(e0, Xh[0], a0, 0, 0, 0);
            a1 = __builtin_amdgcn_mfma_f32_16x16x32_bf16(e1, Xh[0], a1, 0, 0, 0);
        }
        {   // j=3: el c[32,64) x xh
            const short8 e0 = BLD(3, 0), e1 = BLD(3, 1);
            a0 = __builtin_amdgcn_mfma_f32_16x16x32_bf16(e0, Xh[1], a0, 0, 0, 0);
            a1 = __builtin_amdgcn_mfma_f32_16x16x32_bf16(e1, Xh[1], a1, 0, 0, 0);
        }
#undef BLD

        const int cb = K0 + ncol0 + (quad << 2);
#pragma unroll
        for (int reg = 0; reg < 4; ++reg) {
            const float da = a0[reg] + e0v[reg];   // = dot - ||e||^2/2 = -d/2
            if (da > B1a)      { B2a = B1a; I2a = I1a; B1a = da; I1a = cb + reg; }
            else if (da > B2a) { B2a = da; I2a = cb + reg; }
            const float db = a1[reg] + e1v[reg];
            if (db > B1b)      { B2b = B1b; I2b = I1b; B1b = db; I1b = cb + 16 + reg; }
            else if (db > B2b) { B2b = db; I2b = cb + 16 + reg; }
        }
    }

    // ---- merge the two tracks (disjoint code sets, index tie-break) ----
    float B1, B2; int I1, I2;
    if (B1b > B1a || (B1b == B1a && I1b < I1a)) {
        B1 = B1b; I1 = I1b;
        if (B1a > B2b || (B1a == B2b && I1a < I2b)) { B2 = B1a; I2 = I1a; }
        else                                        { B2 = B2b; I2 = I2b; }
    } else {
        B1 = B1a; I1 = I1a;
        if (B1b > B2a || (B1b == B2a && I1b < I2a)) { B2 = B1b; I2 = I1b; }
        else                                        { B2 = B2a; I2 = I2a; }
    }

    // ---- cross-lane top-2 butterfly over QUADS only (off 16,32) ----
#pragma unroll
    for (int off = 16; off <= 32; off <<= 1) {
        const float ob1 = __shfl_xor(B1, off, 64);
        const int   oi1 = __shfl_xor(I1, off, 64);
        const float ob2 = __shfl_xor(B2, off, 64);
        const int   oi2 = __shfl_xor(I2, off, 64);
        if (ob1 > B1 || (ob1 == B1 && oi1 < I1)) {
            float nb2; int ni2;
            if (B1 > ob2 || (B1 == ob2 && I1 < oi2)) { nb2 = B1; ni2 = I1; }
            else                                     { nb2 = ob2; ni2 = oi2; }
            B1 = ob1; I1 = oi1; B2 = nb2; I2 = ni2;
        } else if (ob1 > B2 || (ob1 == B2 && oi1 < I2)) {
            B2 = ob1; I2 = oi1;
        }
    }
    if (lane < 16) {
        b1s[khalf][lane] = B1; b2s[khalf][lane] = B2;
        i1s[khalf][lane] = I1; i2s[khalf][lane] = I2;
    }
    __syncthreads();

    // ---- merge halves -> approx top-2 candidates per row (max-flipped) ----
    if (t < 16) {
        const int r = t;
        float b1 = b1s[0][r], b2 = b2s[0][r];
        int   i1 = i1s[0][r], i2 = i2s[0][r];
        const float c1 = b1s[1][r]; const int j1 = i1s[1][r];
        const float c2 = b2s[1][r]; const int j2 = i2s[1][r];
        if (c1 > b1 || (c1 == b1 && j1 < i1))      { b2 = b1; i2 = i1; b1 = c1; i1 = j1; }
        else if (c1 > b2 || (c1 == b2 && j1 < i2)) { b2 = c1; i2 = j1; }
        if (c2 > b2 || (c2 == b2 && j2 < i2))      { b2 = c2; i2 = j2; }
        c1i[r] = i1; c2i[r] = i2;
    }
    __syncthreads();

    // ---- unconditional 8-way-parallel exact fp64 verify of both candidates:
    // thread group k = t>>4 -> candidate (k&1), c-quarter (k>>1), 16 c each ----
    const int r = t & 15;
    const int k = t >> 4;
    {
        const int cq = k >> 1;
        const int code = (k & 1) ? c2i[r] : c1i[r];
        const float* ep = emb + ((size_t)code << 6) + (cq << 4);
        const float* xq = xb + r;   // lanes r consecutive -> coalesced
        double d0 = 0.0, d1 = 0.0;
#pragma unroll
        for (int cc = 0; cc < 16; cc += 2) {
            const int c = (cq << 4) + cc;
            const double f0 = (double)xq[(size_t)c * HW]       - (double)ep[cc];
            const double f1 = (double)xq[(size_t)(c + 1) * HW] - (double)ep[cc + 1];
            d0 = fma(f0, f0, d0);
            d1 = fma(f1, f1, d1);
        }
        parts[k][r] = d0 + d1;
    }
    __syncthreads();

    // ---- finalize (all threads, redundant per row: LDS broadcast reads) ----
    int win;
    {
        const double d1 = parts[0][r] + parts[2][r] + parts[4][r] + parts[6][r];
        const double d2 = parts[1][r] + parts[3][r] + parts[5][r] + parts[7][r];
        win = c1i[r];
        const int i2 = c2i[r];
        if (d2 < d1 || (d2 == d1 && i2 < win)) win = i2; // lowest-index tie-break
        if (t < 16) idx_out[(blk << 4) + r] = (float)win;
    }

    // ---- epilogue: quantized out (coalesced along w) + per-block SSE ----
    {
        const int c0 = k << 3;           // 8 channels per thread-group
        const float* xp = xb + r;
        float*       op = out + (size_t)b * CHW + h * 64 + (wq << 4) + r;
        const float* eq = emb + ((size_t)win << 6);
        float sse_local = 0.f;
#pragma unroll
        for (int cc = 0; cc < 8; ++cc) {
            const int c = c0 + cc;
            const float qc = eq[c];
            const float dx = qc - xp[(size_t)c * HW];
            sse_local = fmaf(dx, dx, sse_local);
            op[(size_t)c * HW] = qc;
        }
#pragma unroll
        for (int off = 32; off > 0; off >>= 1)
            sse_local += __shfl_down(sse_local, off, 64);
        if (lane == 0) ls_red[wv] = (double)sse_local;
        __syncthreads();
        if (t == 0)
            ws_sse[blk] = ls_red[0] + ls_red[1];   // plain store
    }
}

// tail: 1 block x 512 threads. LDS histogram of all 64K indices (float4
// coalesced reads, LDS atomics only) -> perplexity; ws_sse -> commitment;
// weight -> active codes. Replaces separate hist(16 blocks)+scal(1 block):
// one fewer dispatch+gap, no device-scope atomics, kernel-boundary ordering
// provides coherence with vq_main's plain stores.
__global__ void vq_tail(const float* __restrict__ idx_out,
                        const double* __restrict__ ws_sse,
                        const float* __restrict__ weight,
                        float* __restrict__ scal) {
    __shared__ unsigned hs[512];
    __shared__ double redt[8], reds[8];
    __shared__ int    redi[8];
    const int t = threadIdx.x;       // 0..511 = code
    const int lane = t & 63, wv = t >> 6;
    hs[t] = 0u;
    __syncthreads();
    const float4* ip = (const float4*)idx_out;
#pragma unroll
    for (int i = 0; i < 32; ++i) {
        const float4 v = ip[(i << 9) + t];    // coalesced
        atomicAdd(&hs[(int)v.x], 1u);         // LDS atomics
        atomicAdd(&hs[(int)v.y], 1u);
        atomicAdd(&hs[(int)v.z], 1u);
        atomicAdd(&hs[(int)v.w], 1u);
    }
    __syncthreads();
    const unsigned cnt = hs[t];
    const double pr = (double)cnt / 65536.0;
    double term = pr * log(pr + 1e-10);
    double ssep = 0.0;
#pragma unroll
    for (int j = 0; j < 8; ++j) ssep += ws_sse[t + (j << 9)];   // coalesced
    int act = (weight[t] >= 0.01f) ? 1 : 0;
#pragma unroll
    for (int off = 32; off > 0; off >>= 1) {
        term += __shfl_down(term, off, 64);
        ssep += __shfl_down(ssep, off, 64);
        act  += __shfl_down(act,  off, 64);
    }
    if (lane == 0) { redt[wv] = term; reds[wv] = ssep; redi[wv] = act; }
    __syncthreads();
    if (t == 0) {
        double s = 0.0, ss = 0.0; int a = 0;
#pragma unroll
        for (int i = 0; i < 8; ++i) { s += redt[i]; ss += reds[i]; a += redi[i]; }
        scal[0] = (float)(ss / 4194304.0);  // commitment_loss
        scal[1] = (float)exp(-s);           // perplexity
        scal[2] = (float)a;                 // active_codes
    }
}

extern "C" void kernel_launch(void* const* d_in, const int* in_sizes, int n_in,
                              void* d_out, int out_size, void* d_ws, size_t ws_size,
                              hipStream_t stream) {
    const float* x      = (const float*)d_in[0];  // [16,64,64,64] fp32
    const float* emb    = (const float*)d_in[1];  // [512,64] fp32
    const float* weight = (const float*)d_in[2];  // [512] fp32

    float* out = (float*)d_out;
    float*          enorm  = (float*)d_ws;
    unsigned short* pfrag  = (unsigned short*)((char*)d_ws + 4096);
    double*         ws_sse = (double*)((char*)d_ws + 135168);

    float* scal    = out + OUT_ELEMS;      // commitment, perplexity, active
    float* idx_out = out + OUT_ELEMS + 3;  // indices as float [65536]

    vq_prep<<<128, 256, 0, stream>>>(emb, pfrag, enorm);
    vq_main<<<4096, 128, 0, stream>>>(x, emb, pfrag, enorm, out, idx_out, ws_sse);
    vq_tail<<<1, 512, 0, stream>>>(idx_out, ws_sse, weight, scal);
}

// Round 5
// 104.858 us; speedup vs baseline: 1.1678x; 1.1678x over previous
//
#include <hip/hip_runtime.h>

// Problem constants
#define HW 4096           // H*W
#define CHW 262144        // C*H*W
#define OUT_ELEMS 4194304 // B*C*H*W
#define FLT_BIG 3.4e38f

typedef __attribute__((ext_vector_type(8))) short  short8;   // MFMA A/B frag (4 VGPR)
typedef __attribute__((ext_vector_type(4))) float  floatx4;  // MFMA C/D frag
typedef __attribute__((ext_vector_type(4))) int    intx4;

// ws layout (no zero-init needed -- every byte read is written first):
//   [0,2048)        enorm f32[512]   -- holds -0.5*||e||^2 (prescaled)
//   [4096,135168)   planes_frag u16 (128 KB, fragment-major split-bf16 codebook)
//   [135168,143360) ws_sse double[1024]  (per-block SSE, plain stores)
//   [151552,184320) part u32[16][512]    (per-hist-block partial histograms)

__device__ __forceinline__ unsigned bf16_rne(float f) {
    unsigned u = __float_as_uint(f);
    return (u + 0x7FFFu + ((u >> 16) & 1u)) >> 16;  // RNE bf16 bits
}

__device__ __forceinline__ void split8(const float* f, intx4* hi, intx4* lo) {
    unsigned h[4], l[4];
#pragma unroll
    for (int j = 0; j < 4; ++j) {
        const unsigned h0 = bf16_rne(f[2 * j]);
        const unsigned h1 = bf16_rne(f[2 * j + 1]);
        const float hf0 = __uint_as_float(h0 << 16);
        const float hf1 = __uint_as_float(h1 << 16);
        const unsigned l0 = bf16_rne(f[2 * j] - hf0);
        const unsigned l1 = bf16_rne(f[2 * j + 1] - hf1);
        h[j] = h0 | (h1 << 16);
        l[j] = l0 | (l1 << 16);
    }
    *hi = intx4{(int)h[0], (int)h[1], (int)h[2], (int)h[3]};
    *lo = intx4{(int)l[0], (int)l[1], (int)l[2], (int)l[3]};
}

// prep: 128 blocks x 256 threads; 4 codes/block (1 wave per code), single
// iteration. enorm stored PRESCALED as -0.5*||e||^2.
__global__ void vq_prep(const float* __restrict__ emb,
                        unsigned short* __restrict__ pfrag,
                        float* __restrict__ enorm) {
    const int t = threadIdx.x;
    const int lane = t & 63;
    const int code = (blockIdx.x << 2) + (t >> 6);
    const int c = lane;
    const float v = emb[(code << 6) + c];            // 256B coalesced per wave
    const unsigned hb = bf16_rne(v);
    const float hf    = __uint_as_float(hb << 16);
    const unsigned lb = bf16_rne(v - hf);
    const int nc = code >> 6, grp = (code & 63) >> 4, n = code & 15;
    const int q = (c & 31) >> 3, o = c & 7;
    const int jh = c >> 5;        // eh element e=c
    const int jl = 2 + (c >> 5);  // el element e=64+c
    pfrag[((((size_t)(nc*4 + jh)*4 + grp)*4 + q)*16 + n)*8 + o] = (unsigned short)hb;
    pfrag[((((size_t)(nc*4 + jl)*4 + grp)*4 + q)*16 + n)*8 + o] = (unsigned short)lb;
    float s = v * v;
#pragma unroll
    for (int off = 32; off > 0; off >>= 1) s += __shfl_xor(s, off, 64);
    if (lane == 0) enorm[code] = -0.5f * s;
}

// Main: R16 = R14 core with DOUBLE rows per wave (codebook-fragment reuse).
// 1024 blocks x 256 threads; each block = one full (b,h) 64-w stripe.
// Wave wv: khalf = wv&1 (code-half), mset = wv>>1 (row-set); each wave holds
// TWO register-resident 16-row X-tiles (rows mset*32+{0..15,16..31}) and
// feeds each codebook fragment load (BLD) into BOTH tiles' MFMAs.
// Effect vs R14: codebook L2 traffic halves (512->256 MB), enorm loads halve,
// per-block fixed cost (prologue/syncs/verify/epilogue) amortizes over 2x
// work. R15 post-mortem: per-block work must go UP, not down.
// Carried (R12-R14 verified): swapped MFMA operands (codes=A, x=B; acc IS
// the score), enorm off the MFMA critical path, 2-round butterfly, NO
// device-scope atomics anywhere (R13 post-mortem), 16-block hist (R15 p-m).
__global__ __launch_bounds__(256)
void vq_main(const float* __restrict__ x_in, const float* __restrict__ emb,
             const unsigned short* __restrict__ pfrag,
             const float* __restrict__ enorm,
             float* __restrict__ out, float* __restrict__ idx_out,
             double* __restrict__ ws_sse) {
    __shared__ float  b1s[2][64], b2s[2][64];
    __shared__ int    i1s[2][64], i2s[2][64];
    __shared__ int    c1i[64], c2i[64];
    __shared__ double parts[4][65];
    __shared__ double ls_red[4];

    const int t     = threadIdx.x;
    const int lane  = t & 63;
    const int wv    = t >> 6;           // 0..3
    const int col   = lane & 15;        // w-row within a 16-row M-tile
    const int quad  = lane >> 4;
    const int blk   = blockIdx.x;
    const int khalf = wv & 1;           // code-half of each 64-chunk
    const int mset  = wv >> 1;          // row-set: rows [mset*32, mset*32+32)
    const int ncol0 = khalf << 5;
    const int b = blk >> 6, h = blk & 63;
    const float* xb = x_in + (size_t)b * CHW + h * 64;

    // ---- X-frags: TWO 16-row M-tiles, direct from BCHW global (coalesced),
    // split-bf16, register-resident. Used as the MFMA *B* operand. ----
    short8 Xh[2][2], Xl[2][2];          // [tile][c-half]
#pragma unroll
    for (int T = 0; T < 2; ++T) {
        const int row = (mset << 5) + (T << 4) + col;
#pragma unroll
        for (int u = 0; u < 2; ++u) {
            float f[8];
#pragma unroll
            for (int j = 0; j < 8; ++j) {
                const int c = (u << 5) + (quad << 3) + j;
                f[j] = xb[(size_t)c * HW + row];
            }
            intx4 hi, lo;
            split8(f, &hi, &lo);
            Xh[T][u] = __builtin_bit_cast(short8, hi);
            Xl[T][u] = __builtin_bit_cast(short8, lo);
        }
    }

    // Per-tile, two top-2 tracks (a0/a1) for ILP; merged before butterfly.
    float B1a[2], B2a[2], B1b[2], B2b[2];
    int   I1a[2], I2a[2], I1b[2], I2b[2];
#pragma unroll
    for (int T = 0; T < 2; ++T) {
        B1a[T] = -FLT_BIG; B2a[T] = -FLT_BIG; B1b[T] = -FLT_BIG; B2b[T] = -FLT_BIG;
        I1a[T] = 0x3FFFFFFF; I2a[T] = 0x3FFFFFFF; I1b[T] = 0x3FFFFFFF; I2b[T] = 0x3FFFFFFF;
    }

    const char*  pf  = (const char*)pfrag + (size_t)lane * 16 + ((size_t)khalf << 11);
    const float* enp = enorm + ncol0 + (quad << 2);

#pragma unroll 2
    for (int nc = 0; nc < 8; ++nc) {
        const char* base = pf + ((size_t)nc << 14);
        const int K0 = nc << 6;
        // -0.5*||e||^2 for this lane's 8 codes; shared by BOTH tiles. Loads
        // issue here, first use at selection -> hidden under the MFMA chain.
        const floatx4 e0v = *(const floatx4*)(enp + K0);
        const floatx4 e1v = *(const floatx4*)(enp + K0 + 16);
        floatx4 a0[2] = {{0.f,0.f,0.f,0.f},{0.f,0.f,0.f,0.f}};
        floatx4 a1[2] = {{0.f,0.f,0.f,0.f},{0.f,0.f,0.f,0.f}};
#define BLD(j, g) (*(const short8*)(base + ((j) << 12) + ((g) << 10)))
        {   // j=0: eh c[0,32) x {xh,xl}, both tiles
            const short8 e0 = BLD(0, 0), e1 = BLD(0, 1);
#pragma unroll
            for (int T = 0; T < 2; ++T) {
                a0[T] = __builtin_amdgcn_mfma_f32_16x16x32_bf16(e0, Xh[T][0], a0[T], 0, 0, 0);
                a1[T] = __builtin_amdgcn_mfma_f32_16x16x32_bf16(e1, Xh[T][0], a1[T], 0, 0, 0);
                a0[T] = __builtin_amdgcn_mfma_f32_16x16x32_bf16(e0, Xl[T][0], a0[T], 0, 0, 0);
                a1[T] = __builtin_amdgcn_mfma_f32_16x16x32_bf16(e1, Xl[T][0], a1[T], 0, 0, 0);
            }
        }
        {   // j=1: eh c[32,64) x {xh,xl}, both tiles
            const short8 e0 = BLD(1, 0), e1 = BLD(1, 1);
#pragma unroll
            for (int T = 0; T < 2; ++T) {
                a0[T] = __builtin_amdgcn_mfma_f32_16x16x32_bf16(e0, Xh[T][1], a0[T], 0, 0, 0);
                a1[T] = __builtin_amdgcn_mfma_f32_16x16x32_bf16(e1, Xh[T][1], a1[T], 0, 0, 0);
                a0[T] = __builtin_amdgcn_mfma_f32_16x16x32_bf16(e0, Xl[T][1], a0[T], 0, 0, 0);
                a1[T] = __builtin_amdgcn_mfma_f32_16x16x32_bf16(e1, Xl[T][1], a1[T], 0, 0, 0);
            }
        }
        {   // j=2: el c[0,32) x xh, both tiles
            const short8 e0 = BLD(2, 0), e1 = BLD(2, 1);
#pragma unroll
            for (int T = 0; T < 2; ++T) {
                a0[T] = __builtin_amdgcn_mfma_f32_16x16x32_bf16(e0, Xh[T][0], a0[T], 0, 0, 0);
                a1[T] = __builtin_amdgcn_mfma_f32_16x16x32_bf16(e1, Xh[T][0], a1[T], 0, 0, 0);
            }
        }
        {   // j=3: el c[32,64) x xh, both tiles
            const short8 e0 = BLD(3, 0), e1 = BLD(3, 1);
#pragma unroll
            for (int T = 0; T < 2; ++T) {
                a0[T] = __builtin_amdgcn_mfma_f32_16x16x32_bf16(e0, Xh[T][1], a0[T], 0, 0, 0);
                a1[T] = __builtin_amdgcn_mfma_f32_16x16x32_bf16(e1, Xh[T][1], a1[T], 0, 0, 0);
            }
        }
#undef BLD

        const int cb = K0 + ncol0 + (quad << 2);
#pragma unroll
        for (int T = 0; T < 2; ++T) {
#pragma unroll
            for (int reg = 0; reg < 4; ++reg) {
                const float da = a0[T][reg] + e0v[reg];   // = dot - ||e||^2/2 = -d/2
                if (da > B1a[T])      { B2a[T] = B1a[T]; I2a[T] = I1a[T]; B1a[T] = da; I1a[T] = cb + reg; }
                else if (da > B2a[T]) { B2a[T] = da; I2a[T] = cb + reg; }
                const float db = a1[T][reg] + e1v[reg];
                if (db > B1b[T])      { B2b[T] = B1b[T]; I2b[T] = I1b[T]; B1b[T] = db; I1b[T] = cb + 16 + reg; }
                else if (db > B2b[T]) { B2b[T] = db; I2b[T] = cb + 16 + reg; }
            }
        }
    }

    // ---- per tile: merge tracks, then cross-lane top-2 butterfly over
    // QUADS only (off 16,32); disjoint code sets, explicit index tie-break ----
#pragma unroll
    for (int T = 0; T < 2; ++T) {
        float B1, B2; int I1, I2;
        if (B1b[T] > B1a[T] || (B1b[T] == B1a[T] && I1b[T] < I1a[T])) {
            B1 = B1b[T]; I1 = I1b[T];
            if (B1a[T] > B2b[T] || (B1a[T] == B2b[T] && I1a[T] < I2b[T])) { B2 = B1a[T]; I2 = I1a[T]; }
            else                                                          { B2 = B2b[T]; I2 = I2b[T]; }
        } else {
            B1 = B1a[T]; I1 = I1a[T];
            if (B1b[T] > B2a[T] || (B1b[T] == B2a[T] && I1b[T] < I2a[T])) { B2 = B1b[T]; I2 = I1b[T]; }
            else                                                          { B2 = B2a[T]; I2 = I2a[T]; }
        }
#pragma unroll
        for (int off = 16; off <= 32; off <<= 1) {
            const float ob1 = __shfl_xor(B1, off, 64);
            const int   oi1 = __shfl_xor(I1, off, 64);
            const float ob2 = __shfl_xor(B2, off, 64);
            const int   oi2 = __shfl_xor(I2, off, 64);
            if (ob1 > B1 || (ob1 == B1 && oi1 < I1)) {
                float nb2; int ni2;
                if (B1 > ob2 || (B1 == ob2 && I1 < oi2)) { nb2 = B1; ni2 = I1; }
                else                                     { nb2 = ob2; ni2 = oi2; }
                B1 = ob1; I1 = oi1; B2 = nb2; I2 = ni2;
            } else if (ob1 > B2 || (ob1 == B2 && oi1 < I2)) {
                B2 = ob1; I2 = oi1;
            }
        }
        if (lane < 16) {
            const int row = (mset << 5) + (T << 4) + lane;
            b1s[khalf][row] = B1; b2s[khalf][row] = B2;
            i1s[khalf][row] = I1; i2s[khalf][row] = I2;
        }
    }
    __syncthreads();

    // ---- merge halves -> approx top-2 candidates per row (max-flipped) ----
    if (t < 64) {
        const int r = t;
        float b1 = b1s[0][r], b2 = b2s[0][r];
        int   i1 = i1s[0][r], i2 = i2s[0][r];
        const float c1 = b1s[1][r]; const int j1 = i1s[1][r];
        const float c2 = b2s[1][r]; const int j2 = i2s[1][r];
        if (c1 > b1 || (c1 == b1 && j1 < i1))      { b2 = b1; i2 = i1; b1 = c1; i1 = j1; }
        else if (c1 > b2 || (c1 == b2 && j1 < i2)) { b2 = c1; i2 = j1; }
        if (c2 > b2 || (c2 == b2 && j2 < i2))      { b2 = c2; i2 = j2; }
        c1i[r] = i1; c2i[r] = i2;
    }
    __syncthreads();

    // ---- unconditional 4-way-parallel exact fp64 verify of both candidates:
    // thread group k = t>>6 -> candidate (k&1), c-half (k>>1), 32 c each ----
    const int r = t & 63;
    const int k = t >> 6;
    {
        const int ch = k >> 1;
        const int code = (k & 1) ? c2i[r] : c1i[r];
        const float* ep = emb + ((size_t)code << 6) + (ch << 5);
        const float* xq = xb + r;   // lanes r consecutive -> coalesced
        double d0 = 0.0, d1 = 0.0;
#pragma unroll
        for (int cc = 0; cc < 32; cc += 2) {
            const int c = (ch << 5) + cc;
            const double f0 = (double)xq[(size_t)c * HW]       - (double)ep[cc];
            const double f1 = (double)xq[(size_t)(c + 1) * HW] - (double)ep[cc + 1];
            d0 = fma(f0, f0, d0);
            d1 = fma(f1, f1, d1);
        }
        parts[k][r] = d0 + d1;
    }
    __syncthreads();

    // ---- finalize (all threads, redundant per row: LDS broadcast reads) ----
    int win;
    {
        const double d1 = parts[0][r] + parts[2][r];
        const double d2 = parts[1][r] + parts[3][r];
        win = c1i[r];
        const int i2 = c2i[r];
        if (d2 < d1 || (d2 == d1 && i2 < win)) win = i2; // lowest-index tie-break
        if (t < 64) idx_out[(blk << 6) + r] = (float)win;
    }

    // ---- epilogue: quantized out (coalesced along w) + per-block SSE ----
    {
        const int c0 = k << 4;           // 16 channels per thread-group
        const float* xp = xb + r;
        float*       op = out + (size_t)b * CHW + h * 64 + r;
        const float* eq = emb + ((size_t)win << 6);
        float sse_local = 0.f;
#pragma unroll
        for (int cc = 0; cc < 16; ++cc) {
            const int c = c0 + cc;
            const float qc = eq[c];
            const float dx = qc - xp[(size_t)c * HW];
            sse_local = fmaf(dx, dx, sse_local);
            op[(size_t)c * HW] = qc;
        }
#pragma unroll
        for (int off = 32; off > 0; off >>= 1)
            sse_local += __shfl_down(sse_local, off, 64);
        if (lane == 0) ls_red[wv] = (double)sse_local;
        __syncthreads();
        if (t == 0)
            ws_sse[blk] = (ls_red[0] + ls_red[1]) + (ls_red[2] + ls_red[3]);  // plain store
    }
}

// hist: 16 blocks x 256 threads; LDS histogram of 4096 indices each, plain
// partial-store. Kernel-boundary ordering provides coherence (R9-proven).
__global__ void vq_hist(const float* __restrict__ idx_out,
                        unsigned* __restrict__ part) {
    __shared__ unsigned hs[512];
    const int t = threadIdx.x;
    hs[t] = 0u; hs[t + 256] = 0u;
    __syncthreads();
    const float4* ip = (const float4*)(idx_out + (blockIdx.x << 12));
#pragma unroll
    for (int i = 0; i < 4; ++i) {
        const float4 v = ip[(i << 8) + t];    // coalesced
        atomicAdd(&hs[(int)v.x], 1u);         // LDS atomics
        atomicAdd(&hs[(int)v.y], 1u);
        atomicAdd(&hs[(int)v.z], 1u);
        atomicAdd(&hs[(int)v.w], 1u);
    }
    __syncthreads();
    unsigned* pp = part + (blockIdx.x << 9);
    pp[t] = hs[t]; pp[t + 256] = hs[t + 256];  // coalesced plain stores
}

// scal: 1 block x 512 threads. Partial hists -> perplexity; ws_sse ->
// commitment; weight -> active codes.
__global__ void vq_scal(const unsigned* __restrict__ part,
                        const double* __restrict__ ws_sse,
                        const float* __restrict__ weight,
                        float* __restrict__ scal) {
    __shared__ double redt[8], reds[8];
    __shared__ int    redi[8];
    const int k = threadIdx.x;       // 0..511 = code
    const int lane = k & 63, wv = k >> 6;
    unsigned cnt = 0;
#pragma unroll
    for (int p = 0; p < 16; ++p) cnt += part[(p << 9) + k];   // coalesced per p
    const double pr = (double)cnt / 65536.0;
    double term = pr * log(pr + 1e-10);
    double ssep = 0.0;
#pragma unroll
    for (int j = 0; j < 2; ++j) ssep += ws_sse[k + (j << 9)];
    int act = (weight[k] >= 0.01f) ? 1 : 0;
#pragma unroll
    for (int off = 32; off > 0; off >>= 1) {
        term += __shfl_down(term, off, 64);
        ssep += __shfl_down(ssep, off, 64);
        act  += __shfl_down(act,  off, 64);
    }
    if (lane == 0) { redt[wv] = term; reds[wv] = ssep; redi[wv] = act; }
    __syncthreads();
    if (k == 0) {
        double s = 0.0, ss = 0.0; int a = 0;
#pragma unroll
        for (int i = 0; i < 8; ++i) { s += redt[i]; ss += reds[i]; a += redi[i]; }
        scal[0] = (float)(ss / 4194304.0);  // commitment_loss
        scal[1] = (float)exp(-s);           // perplexity
        scal[2] = (float)a;                 // active_codes
    }
}

extern "C" void kernel_launch(void* const* d_in, const int* in_sizes, int n_in,
                              void* d_out, int out_size, void* d_ws, size_t ws_size,
                              hipStream_t stream) {
    const float* x      = (const float*)d_in[0];  // [16,64,64,64] fp32
    const float* emb    = (const float*)d_in[1];  // [512,64] fp32
    const float* weight = (const float*)d_in[2];  // [512] fp32

    float* out = (float*)d_out;
    float*          enorm  = (float*)d_ws;
    unsigned short* pfrag  = (unsigned short*)((char*)d_ws + 4096);
    double*         ws_sse = (double*)((char*)d_ws + 135168);
    unsigned*       part   = (unsigned*)((char*)d_ws + 151552);

    float* scal    = out + OUT_ELEMS;      // commitment, perplexity, active
    float* idx_out = out + OUT_ELEMS + 3;  // indices as float [65536]

    vq_prep<<<128, 256, 0, stream>>>(emb, pfrag, enorm);
    vq_main<<<1024, 256, 0, stream>>>(x, emb, pfrag, enorm, out, idx_out, ws_sse);
    vq_hist<<<16, 256, 0, stream>>>(idx_out, part);
    vq_scal<<<1, 512, 0, stream>>>(part, ws_sse, weight, scal);
}

// Round 6
// 102.592 us; speedup vs baseline: 1.1936x; 1.0221x over previous
//
#include <hip/hip_runtime.h>

// Problem constants
#define HW 4096           // H*W
#define CHW 262144        // C*H*W
#define OUT_ELEMS 4194304 // B*C*H*W
#define FLT_BIG 3.4e38f

typedef __attribute__((ext_vector_type(8))) short  short8;   // MFMA A/B frag (4 VGPR)
typedef __attribute__((ext_vector_type(4))) float  floatx4;  // MFMA C/D frag
typedef __attribute__((ext_vector_type(4))) int    intx4;

// ws layout:
//   [0,2048)        enorm f32[512]   -- holds -0.5*||e||^2 (prescaled)
//   [4096,135168)   planes_frag u16 (128 KB, fragment-major split-bf16 codebook)
//   [135168,143360) ws_sse double[1024]  (per-block SSE, plain stores)
//   [143360,145408) hist u32[512]    (device-atomic accumulated histogram)
//   [145408,145412) done u32         (hist2 block completion counter)
// hist/done zeroed by vq_prep block 0 each launch (graph-replay safe).

__device__ __forceinline__ unsigned bf16_rne(float f) {
    unsigned u = __float_as_uint(f);
    return (u + 0x7FFFu + ((u >> 16) & 1u)) >> 16;  // RNE bf16 bits
}

__device__ __forceinline__ void split8(const float* f, intx4* hi, intx4* lo) {
    unsigned h[4], l[4];
#pragma unroll
    for (int j = 0; j < 4; ++j) {
        const unsigned h0 = bf16_rne(f[2 * j]);
        const unsigned h1 = bf16_rne(f[2 * j + 1]);
        const float hf0 = __uint_as_float(h0 << 16);
        const float hf1 = __uint_as_float(h1 << 16);
        const unsigned l0 = bf16_rne(f[2 * j] - hf0);
        const unsigned l1 = bf16_rne(f[2 * j + 1] - hf1);
        h[j] = h0 | (h1 << 16);
        l[j] = l0 | (l1 << 16);
    }
    *hi = intx4{(int)h[0], (int)h[1], (int)h[2], (int)h[3]};
    *lo = intx4{(int)l[0], (int)l[1], (int)l[2], (int)l[3]};
}

// prep: 128 blocks x 256 threads; 4 codes/block (1 wave per code), single
// iteration. enorm stored PRESCALED as -0.5*||e||^2. Block 0 also zeroes
// hist/done for the fused hist2 tail.
__global__ void vq_prep(const float* __restrict__ emb,
                        unsigned short* __restrict__ pfrag,
                        float* __restrict__ enorm,
                        unsigned* __restrict__ hist,
                        unsigned* __restrict__ done) {
    const int t = threadIdx.x;
    const int lane = t & 63;
    if (blockIdx.x == 0) {
        hist[t] = 0u; hist[t + 256] = 0u;
        if (t == 0) *done = 0u;
    }
    const int code = (blockIdx.x << 2) + (t >> 6);
    const int c = lane;
    const float v = emb[(code << 6) + c];            // 256B coalesced per wave
    const unsigned hb = bf16_rne(v);
    const float hf    = __uint_as_float(hb << 16);
    const unsigned lb = bf16_rne(v - hf);
    const int nc = code >> 6, grp = (code & 63) >> 4, n = code & 15;
    const int q = (c & 31) >> 3, o = c & 7;
    const int jh = c >> 5;        // eh element e=c
    const int jl = 2 + (c >> 5);  // el element e=64+c
    pfrag[((((size_t)(nc*4 + jh)*4 + grp)*4 + q)*16 + n)*8 + o] = (unsigned short)hb;
    pfrag[((((size_t)(nc*4 + jl)*4 + grp)*4 + q)*16 + n)*8 + o] = (unsigned short)lb;
    float s = v * v;
#pragma unroll
    for (int off = 32; off > 0; off >>= 1) s += __shfl_xor(s, off, 64);
    if (lane == 0) enorm[code] = -0.5f * s;
}

// Main: R17 = R16 geometry (1024 blocks x 256 thr, 2 tiles/wave) with the
// codebook stream moved through LDS (double-buffered 16 KB/nc slices).
// R16's measured -3.7us matched the L2-halving arithmetic exactly, so apply
// the same lever again: per block, the 4 waves issued 256 KB of L2 reads for
// 128 KB unique; staging each nc slice once (reg-staged intx4 -> ds_write)
// cuts block traffic to 128 KB -> 128 MB total. LDS 32 KB + 3.6 KB keeps
// 4 blocks/CU (16 waves/CU) -- occupancy unchanged (R15 lesson: never trade
// supply away). One barrier per nc (double buffer gives one-iter slack).
// Carried: swapped MFMA operands (codes=A, x=B), enorm off the MFMA critical
// path, 2-round butterfly, NO device atomics in this kernel.
__global__ __launch_bounds__(256)
void vq_main(const float* __restrict__ x_in, const float* __restrict__ emb,
             const unsigned short* __restrict__ pfrag,
             const float* __restrict__ enorm,
             float* __restrict__ out, float* __restrict__ idx_out,
             double* __restrict__ ws_sse) {
    __shared__ unsigned short cbuf[2][8192];   // 2 x 16 KB codebook slices
    __shared__ float  b1s[2][64], b2s[2][64];
    __shared__ int    i1s[2][64], i2s[2][64];
    __shared__ int    c1i[64], c2i[64];
    __shared__ double parts[4][65];
    __shared__ double ls_red[4];

    const int t     = threadIdx.x;
    const int lane  = t & 63;
    const int wv    = t >> 6;           // 0..3
    const int col   = lane & 15;        // w-row within a 16-row M-tile
    const int quad  = lane >> 4;
    const int blk   = blockIdx.x;
    const int khalf = wv & 1;           // code-half of each 64-chunk
    const int mset  = wv >> 1;          // row-set: rows [mset*32, mset*32+32)
    const int ncol0 = khalf << 5;
    const int b = blk >> 6, h = blk & 63;
    const float* xb = x_in + (size_t)b * CHW + h * 64;

    // ---- issue slice-0 staging loads FIRST (latency hides under split8) ----
    intx4 s0[4];
#pragma unroll
    for (int i = 0; i < 4; ++i)
        s0[i] = *(const intx4*)((const char*)pfrag + (i << 12) + (t << 4));

    // ---- X-frags: TWO 16-row M-tiles, direct from BCHW global (coalesced),
    // split-bf16, register-resident. Used as the MFMA *B* operand. ----
    short8 Xh[2][2], Xl[2][2];          // [tile][c-half]
#pragma unroll
    for (int T = 0; T < 2; ++T) {
        const int row = (mset << 5) + (T << 4) + col;
#pragma unroll
        for (int u = 0; u < 2; ++u) {
            float f[8];
#pragma unroll
            for (int j = 0; j < 8; ++j) {
                const int c = (u << 5) + (quad << 3) + j;
                f[j] = xb[(size_t)c * HW + row];
            }
            intx4 hi, lo;
            split8(f, &hi, &lo);
            Xh[T][u] = __builtin_bit_cast(short8, hi);
            Xl[T][u] = __builtin_bit_cast(short8, lo);
        }
    }

    // ---- write slice 0 into LDS buffer 0 ----
#pragma unroll
    for (int i = 0; i < 4; ++i)
        *(intx4*)((char*)&cbuf[0][0] + (i << 12) + (t << 4)) = s0[i];
    __syncthreads();

    // Per-tile, two top-2 tracks (a0/a1) for ILP; merged before butterfly.
    float B1a[2], B2a[2], B1b[2], B2b[2];
    int   I1a[2], I2a[2], I1b[2], I2b[2];
#pragma unroll
    for (int T = 0; T < 2; ++T) {
        B1a[T] = -FLT_BIG; B2a[T] = -FLT_BIG; B1b[T] = -FLT_BIG; B2b[T] = -FLT_BIG;
        I1a[T] = 0x3FFFFFFF; I2a[T] = 0x3FFFFFFF; I1b[T] = 0x3FFFFFFF; I2b[T] = 0x3FFFFFFF;
    }

    const float* enp = enorm + ncol0 + (quad << 2);
    const int lbo = (khalf << 11) + (lane << 4);   // within-slice lane base

#pragma unroll 2
    for (int nc = 0; nc < 8; ++nc) {
        const int cur = nc & 1;
        // early-issue next slice's global loads (consumed after compute)
        intx4 st[4];
        if (nc < 7) {
#pragma unroll
            for (int i = 0; i < 4; ++i)
                st[i] = *(const intx4*)((const char*)pfrag +
                          ((size_t)(nc + 1) << 14) + (i << 12) + (t << 4));
        }
        const int K0 = nc << 6;
        // -0.5*||e||^2 for this lane's 8 codes; shared by BOTH tiles.
        const floatx4 e0v = *(const floatx4*)(enp + K0);
        const floatx4 e1v = *(const floatx4*)(enp + K0 + 16);
        floatx4 a0[2] = {{0.f,0.f,0.f,0.f},{0.f,0.f,0.f,0.f}};
        floatx4 a1[2] = {{0.f,0.f,0.f,0.f},{0.f,0.f,0.f,0.f}};
        const char* base = (const char*)&cbuf[cur][0] + lbo;
#define BLD(j, g) (*(const short8*)(base + ((j) << 12) + ((g) << 10)))
        {   // j=0: eh c[0,32) x {xh,xl}, both tiles
            const short8 e0 = BLD(0, 0), e1 = BLD(0, 1);
#pragma unroll
            for (int T = 0; T < 2; ++T) {
                a0[T] = __builtin_amdgcn_mfma_f32_16x16x32_bf16(e0, Xh[T][0], a0[T], 0, 0, 0);
                a1[T] = __builtin_amdgcn_mfma_f32_16x16x32_bf16(e1, Xh[T][0], a1[T], 0, 0, 0);
                a0[T] = __builtin_amdgcn_mfma_f32_16x16x32_bf16(e0, Xl[T][0], a0[T], 0, 0, 0);
                a1[T] = __builtin_amdgcn_mfma_f32_16x16x32_bf16(e1, Xl[T][0], a1[T], 0, 0, 0);
            }
        }
        {   // j=1: eh c[32,64) x {xh,xl}, both tiles
            const short8 e0 = BLD(1, 0), e1 = BLD(1, 1);
#pragma unroll
            for (int T = 0; T < 2; ++T) {
                a0[T] = __builtin_amdgcn_mfma_f32_16x16x32_bf16(e0, Xh[T][1], a0[T], 0, 0, 0);
                a1[T] = __builtin_amdgcn_mfma_f32_16x16x32_bf16(e1, Xh[T][1], a1[T], 0, 0, 0);
                a0[T] = __builtin_amdgcn_mfma_f32_16x16x32_bf16(e0, Xl[T][1], a0[T], 0, 0, 0);
                a1[T] = __builtin_amdgcn_mfma_f32_16x16x32_bf16(e1, Xl[T][1], a1[T], 0, 0, 0);
            }
        }
        {   // j=2: el c[0,32) x xh, both tiles
            const short8 e0 = BLD(2, 0), e1 = BLD(2, 1);
#pragma unroll
            for (int T = 0; T < 2; ++T) {
                a0[T] = __builtin_amdgcn_mfma_f32_16x16x32_bf16(e0, Xh[T][0], a0[T], 0, 0, 0);
                a1[T] = __builtin_amdgcn_mfma_f32_16x16x32_bf16(e1, Xh[T][0], a1[T], 0, 0, 0);
            }
        }
        {   // j=3: el c[32,64) x xh, both tiles
            const short8 e0 = BLD(3, 0), e1 = BLD(3, 1);
#pragma unroll
            for (int T = 0; T < 2; ++T) {
                a0[T] = __builtin_amdgcn_mfma_f32_16x16x32_bf16(e0, Xh[T][1], a0[T], 0, 0, 0);
                a1[T] = __builtin_amdgcn_mfma_f32_16x16x32_bf16(e1, Xh[T][1], a1[T], 0, 0, 0);
            }
        }
#undef BLD

        const int cb = K0 + ncol0 + (quad << 2);
#pragma unroll
        for (int T = 0; T < 2; ++T) {
#pragma unroll
            for (int reg = 0; reg < 4; ++reg) {
                const float da = a0[T][reg] + e0v[reg];   // = dot - ||e||^2/2 = -d/2
                if (da > B1a[T])      { B2a[T] = B1a[T]; I2a[T] = I1a[T]; B1a[T] = da; I1a[T] = cb + reg; }
                else if (da > B2a[T]) { B2a[T] = da; I2a[T] = cb + reg; }
                const float db = a1[T][reg] + e1v[reg];
                if (db > B1b[T])      { B2b[T] = B1b[T]; I2b[T] = I1b[T]; B1b[T] = db; I1b[T] = cb + 16 + reg; }
                else if (db > B2b[T]) { B2b[T] = db; I2b[T] = cb + 16 + reg; }
            }
        }

        // write next slice into the other buffer; barrier covers both the
        // ds_writes (producers) and this iteration's ds_reads (consumers).
        if (nc < 7) {
#pragma unroll
            for (int i = 0; i < 4; ++i)
                *(intx4*)((char*)&cbuf[cur ^ 1][0] + (i << 12) + (t << 4)) = st[i];
        }
        __syncthreads();
    }

    // ---- per tile: merge tracks, then cross-lane top-2 butterfly over
    // QUADS only (off 16,32); disjoint code sets, explicit index tie-break ----
#pragma unroll
    for (int T = 0; T < 2; ++T) {
        float B1, B2; int I1, I2;
        if (B1b[T] > B1a[T] || (B1b[T] == B1a[T] && I1b[T] < I1a[T])) {
            B1 = B1b[T]; I1 = I1b[T];
            if (B1a[T] > B2b[T] || (B1a[T] == B2b[T] && I1a[T] < I2b[T])) { B2 = B1a[T]; I2 = I1a[T]; }
            else                                                          { B2 = B2b[T]; I2 = I2b[T]; }
        } else {
            B1 = B1a[T]; I1 = I1a[T];
            if (B1b[T] > B2a[T] || (B1b[T] == B2a[T] && I1b[T] < I2a[T])) { B2 = B1b[T]; I2 = I1b[T]; }
            else                                                          { B2 = B2a[T]; I2 = I2a[T]; }
        }
#pragma unroll
        for (int off = 16; off <= 32; off <<= 1) {
            const float ob1 = __shfl_xor(B1, off, 64);
            const int   oi1 = __shfl_xor(I1, off, 64);
            const float ob2 = __shfl_xor(B2, off, 64);
            const int   oi2 = __shfl_xor(I2, off, 64);
            if (ob1 > B1 || (ob1 == B1 && oi1 < I1)) {
                float nb2; int ni2;
                if (B1 > ob2 || (B1 == ob2 && I1 < oi2)) { nb2 = B1; ni2 = I1; }
                else                                     { nb2 = ob2; ni2 = oi2; }
                B1 = ob1; I1 = oi1; B2 = nb2; I2 = ni2;
            } else if (ob1 > B2 || (ob1 == B2 && oi1 < I2)) {
                B2 = ob1; I2 = oi1;
            }
        }
        if (lane < 16) {
            const int row = (mset << 5) + (T << 4) + lane;
            b1s[khalf][row] = B1; b2s[khalf][row] = B2;
            i1s[khalf][row] = I1; i2s[khalf][row] = I2;
        }
    }
    __syncthreads();

    // ---- merge halves -> approx top-2 candidates per row (max-flipped) ----
    if (t < 64) {
        const int r = t;
        float b1 = b1s[0][r], b2 = b2s[0][r];
        int   i1 = i1s[0][r], i2 = i2s[0][r];
        const float c1 = b1s[1][r]; const int j1 = i1s[1][r];
        const float c2 = b2s[1][r]; const int j2 = i2s[1][r];
        if (c1 > b1 || (c1 == b1 && j1 < i1))      { b2 = b1; i2 = i1; b1 = c1; i1 = j1; }
        else if (c1 > b2 || (c1 == b2 && j1 < i2)) { b2 = c1; i2 = j1; }
        if (c2 > b2 || (c2 == b2 && j2 < i2))      { b2 = c2; i2 = j2; }
        c1i[r] = i1; c2i[r] = i2;
    }
    __syncthreads();

    // ---- unconditional 4-way-parallel exact fp64 verify of both candidates:
    // thread group k = t>>6 -> candidate (k&1), c-half (k>>1), 32 c each ----
    const int r = t & 63;
    const int k = t >> 6;
    {
        const int ch = k >> 1;
        const int code = (k & 1) ? c2i[r] : c1i[r];
        const float* ep = emb + ((size_t)code << 6) + (ch << 5);
        const float* xq = xb + r;   // lanes r consecutive -> coalesced
        double d0 = 0.0, d1 = 0.0;
#pragma unroll
        for (int cc = 0; cc < 32; cc += 2) {
            const int c = (ch << 5) + cc;
            const double f0 = (double)xq[(size_t)c * HW]       - (double)ep[cc];
            const double f1 = (double)xq[(size_t)(c + 1) * HW] - (double)ep[cc + 1];
            d0 = fma(f0, f0, d0);
            d1 = fma(f1, f1, d1);
        }
        parts[k][r] = d0 + d1;
    }
    __syncthreads();

    // ---- finalize (all threads, redundant per row: LDS broadcast reads) ----
    int win;
    {
        const double d1 = parts[0][r] + parts[2][r];
        const double d2 = parts[1][r] + parts[3][r];
        win = c1i[r];
        const int i2 = c2i[r];
        if (d2 < d1 || (d2 == d1 && i2 < win)) win = i2; // lowest-index tie-break
        if (t < 64) idx_out[(blk << 6) + r] = (float)win;
    }

    // ---- epilogue: quantized out (coalesced along w) + per-block SSE ----
    {
        const int c0 = k << 4;           // 16 channels per thread-group
        const float* xp = xb + r;
        float*       op = out + (size_t)b * CHW + h * 64 + r;
        const float* eq = emb + ((size_t)win << 6);
        float sse_local = 0.f;
#pragma unroll
        for (int cc = 0; cc < 16; ++cc) {
            const int c = c0 + cc;
            const float qc = eq[c];
            const float dx = qc - xp[(size_t)c * HW];
            sse_local = fmaf(dx, dx, sse_local);
            op[(size_t)c * HW] = qc;
        }
#pragma unroll
        for (int off = 32; off > 0; off >>= 1)
            sse_local += __shfl_down(sse_local, off, 64);
        if (lane == 0) ls_red[wv] = (double)sse_local;
        __syncthreads();
        if (t == 0)
            ws_sse[blk] = (ls_red[0] + ls_red[1]) + (ls_red[2] + ls_red[3]);  // plain store
    }
}

// hist2: 16 blocks x 256 threads. LDS histogram of 4096 indices each, pushed
// into a global hist via device atomicAdd (8K adds total -- negligible at
// this block count, unlike R12/R13's 2048-block version), then a done-counter
// last block computes all three scalars. Fence-free R13 pattern: atomics are
// performed at the coherent point; the pre-bump __syncthreads drains every
// thread's adds (compiler emits vmcnt(0) before s_barrier); acquire side
// reads hist via relaxed agent atomic loads. ws_sse/weight are plain reads
// of prior-dispatch data (kernel-boundary coherence, R9-proven).
__global__ void vq_hist2(const float* __restrict__ idx_out,
                         const double* __restrict__ ws_sse,
                         const float* __restrict__ weight,
                         unsigned* __restrict__ hist,
                         unsigned* __restrict__ done,
                         float* __restrict__ scal) {
    __shared__ unsigned hs[512];
    __shared__ double redt[4], reds[4];
    __shared__ int    redi[4], lastf;
    const int t = threadIdx.x;
    const int lane = t & 63, wv = t >> 6;
    hs[t] = 0u; hs[t + 256] = 0u;
    __syncthreads();
    const float4* ip = (const float4*)(idx_out + (blockIdx.x << 12));
#pragma unroll
    for (int i = 0; i < 4; ++i) {
        const float4 v = ip[(i << 8) + t];    // coalesced
        atomicAdd(&hs[(int)v.x], 1u);         // LDS atomics
        atomicAdd(&hs[(int)v.y], 1u);
        atomicAdd(&hs[(int)v.z], 1u);
        atomicAdd(&hs[(int)v.w], 1u);
    }
    __syncthreads();
    if (hs[t])       atomicAdd(&hist[t],       hs[t]);
    if (hs[t + 256]) atomicAdd(&hist[t + 256], hs[t + 256]);
    __syncthreads();   // drains every thread's global atomics (vmcnt 0)

    if (t == 0) {
        lastf = (__hip_atomic_fetch_add(done, 1u, __ATOMIC_RELAXED,
                                        __HIP_MEMORY_SCOPE_AGENT) == 15u) ? 1 : 0;
    }
    __syncthreads();
    if (lastf) {
        double term = 0.0, ssep = 0.0; int act = 0;
#pragma unroll
        for (int j = 0; j < 2; ++j) {
            const int kk = t + (j << 8);
            const unsigned cnt =
                __hip_atomic_load(&hist[kk], __ATOMIC_RELAXED, __HIP_MEMORY_SCOPE_AGENT);
            const double pr = (double)cnt * (1.0 / 65536.0);
            term += pr * log(pr + 1e-10);
            act  += (weight[kk] >= 0.01f) ? 1 : 0;
        }
#pragma unroll
        for (int j = 0; j < 4; ++j) ssep += ws_sse[t + (j << 8)];   // coalesced
#pragma unroll
        for (int off = 32; off > 0; off >>= 1) {
            term += __shfl_down(term, off, 64);
            ssep += __shfl_down(ssep, off, 64);
            act  += __shfl_down(act,  off, 64);
        }
        if (lane == 0) { redt[wv] = term; reds[wv] = ssep; redi[wv] = act; }
        __syncthreads();
        if (t == 0) {
            const double s  = (redt[0] + redt[1]) + (redt[2] + redt[3]);
            const double ss = (reds[0] + reds[1]) + (reds[2] + reds[3]);
            const int    a  = redi[0] + redi[1] + redi[2] + redi[3];
            scal[0] = (float)(ss * (1.0 / 4194304.0));  // commitment_loss
            scal[1] = (float)exp(-s);                   // perplexity
            scal[2] = (float)a;                         // active_codes
        }
    }
}

extern "C" void kernel_launch(void* const* d_in, const int* in_sizes, int n_in,
                              void* d_out, int out_size, void* d_ws, size_t ws_size,
                              hipStream_t stream) {
    const float* x      = (const float*)d_in[0];  // [16,64,64,64] fp32
    const float* emb    = (const float*)d_in[1];  // [512,64] fp32
    const float* weight = (const float*)d_in[2];  // [512] fp32

    float* out = (float*)d_out;
    float*          enorm  = (float*)d_ws;
    unsigned short* pfrag  = (unsigned short*)((char*)d_ws + 4096);
    double*         ws_sse = (double*)((char*)d_ws + 135168);
    unsigned*       hist   = (unsigned*)((char*)d_ws + 143360);
    unsigned*       done   = (unsigned*)((char*)d_ws + 145408);

    float* scal    = out + OUT_ELEMS;      // commitment, perplexity, active
    float* idx_out = out + OUT_ELEMS + 3;  // indices as float [65536]

    vq_prep<<<128, 256, 0, stream>>>(emb, pfrag, enorm, hist, done);
    vq_main<<<1024, 256, 0, stream>>>(x, emb, pfrag, enorm, out, idx_out, ws_sse);
    vq_hist2<<<16, 256, 0, stream>>>(idx_out, ws_sse, weight, hist, done, scal);
}